// Round 1
// baseline (2926.122 us; speedup 1.0000x reference)
//
#include <hip/hip_runtime.h>
#include <hip/hip_bf16.h>

#define N 4096
#define B 8
#define ITERS 10
#define T (ITERS * N)
#define NT 256          // 4 waves
#define E 16            // field elements per thread
#define WIN 1024
#define INFK 0xFFFFFFFFu
#define LIMIT 0x01000000u

// ---- LDS-only barrier -------------------------------------------------------
// __syncthreads() compiles to "s_waitcnt vmcnt(0) lgkmcnt(0); s_barrier": it
// drains the in-flight prefetch row loads (which target REGISTERS and need no
// cross-wave visibility) on every round -> ~full L3/HBM latency added per
// round, defeating the prefetch. The inner loop's only cross-wave traffic is
// the LDS slot publish, which needs lgkmcnt(0) only. Parity-buffered slots
// make the single-barrier protocol race-free (writer hits slot[p^1] while the
// slowest reader is still on slot[p]; all waves cross each barrier together).
__device__ __forceinline__ void lds_barrier() {
    asm volatile("s_waitcnt lgkmcnt(0)\n\ts_barrier" ::: "memory");
}

// Kernel 1: Z0[b][i] = sum_j W[i][j] * x[b][j], accumulated in double.
// Vectorized: float4 row + float4 x loads (was scalar -> ~700 GB/s), DPP/shfl
// wave reduction instead of 8 barrier rounds. f32*f32 products in double are
// exact; only add-rounding order changes (|z| ~ 1e-2 >> 1e-16 perturbation).
__global__ __launch_bounds__(256) void z0_gemv(const float* __restrict__ W,
                                               const float* __restrict__ x,
                                               double* __restrict__ Z0) {
    const int i = blockIdx.x;
    const int tid = threadIdx.x;
    const int lane = tid & 63;
    const int wid = tid >> 6;
    const float4* __restrict__ row = (const float4*)(W + (size_t)i * N);
    const float4* __restrict__ xv = (const float4*)x;

    double acc[B];
#pragma unroll
    for (int b = 0; b < B; ++b) acc[b] = 0.0;

#pragma unroll
    for (int it = 0; it < 4; ++it) {
        const int c = tid + 256 * it;
        const float4 w = row[c];
#pragma unroll
        for (int b = 0; b < B; ++b) {
            const float4 xb = xv[b * (N / 4) + c];
            acc[b] += (double)w.x * (double)xb.x + (double)w.y * (double)xb.y +
                      (double)w.z * (double)xb.z + (double)w.w * (double)xb.w;
        }
    }

#pragma unroll
    for (int off = 32; off > 0; off >>= 1) {
#pragma unroll
        for (int b = 0; b < B; ++b) acc[b] += __shfl_down(acc[b], off, 64);
    }

    __shared__ double red[4][B];
    if (lane == 0) {
#pragma unroll
        for (int b = 0; b < B; ++b) red[wid][b] = acc[b];
    }
    __syncthreads();
    if (tid < B)
        Z0[(size_t)tid * N + i] = red[0][tid] + red[1][tid] + red[2][tid] + red[3][tid];
}

__device__ __forceinline__ unsigned umin2(unsigned a, unsigned b) { return a < b ? a : b; }

// One DPP min step. CTRL must be an immediate -> template parameter.
// Lanes with no valid source keep their own value (old=v, bound_ctrl=false),
// so the min is unaffected.
template <int CTRL>
__device__ __forceinline__ unsigned dpp_min(unsigned v) {
    const int t = __builtin_amdgcn_update_dpp((int)v, (int)v, CTRL, 0xF, 0xF, false);
    return umin2(v, (unsigned)t);
}

// Full wave64 min via DPP (~6 VALU-latency steps, no LDS). Valid in lane 63;
// returned as a wave-uniform value via readlane.
__device__ __forceinline__ unsigned wave_min64(unsigned v) {
    v = dpp_min<0x111>(v);  // row_shr:1
    v = dpp_min<0x112>(v);  // row_shr:2
    v = dpp_min<0x114>(v);  // row_shr:4
    v = dpp_min<0x118>(v);  // row_shr:8
    v = dpp_min<0x142>(v);  // row_bcast:15
    v = dpp_min<0x143>(v);  // row_bcast:31
    return (unsigned)__builtin_amdgcn_readlane((int)v, 63);
}

// Kernel 2: 4-wave register-resident scan. Structure identical to the previous
// round except both inner barriers are lgkmcnt-only (lds_barrier), so the
// prefetched winner/candidate rows stay in flight across barriers.
// Key algebra unchanged: sk = pos<<14 | i<<2 | (y+1); per elem per round:
//  zj += d*w; t2 = hi64(zj) ^ ymask; cand = (sk | (t2>>31)) - ck; min.
// Mismatch => s=-y => d=-2*y1; winner decoded wholly from the key.
__global__ __launch_bounds__(256) void hop_seq(const float* __restrict__ W,
                                               const float* __restrict__ x,
                                               const int* __restrict__ perms,
                                               const double* __restrict__ Z0,
                                               float* __restrict__ out) {
    const int b = blockIdx.x;
    const int tid = threadIdx.x;
    const int wid = tid >> 6;
    const int lane = tid & 63;

    __shared__ int wpos[N];        // 16 KB epoch-tagged inverse map
    __shared__ uint4 slot1v[2];    // per-wave min, parity buffered
    __shared__ uint4 slot2v[2];    // per-wave 2nd min, parity buffered

    // ---- register-resident field ----
    double zj[E];
    unsigned ymask[E];             // 0xFFFFFFFF if y>0 else 0x7FFFFFFF
    unsigned sk[E];
    {
        const double* __restrict__ zsrc = Z0 + (size_t)b * N + E * tid;
#pragma unroll
        for (int k = 0; k < E; ++k) zj[k] = zsrc[k];
        const float4* __restrict__ xs = (const float4*)(x + (size_t)b * N);
#pragma unroll
        for (int q = 0; q < 4; ++q) {
            const float4 xv = xs[4 * tid + q];
            ymask[4 * q + 0] = (xv.x > 0.f) ? 0xFFFFFFFFu : 0x7FFFFFFFu;
            ymask[4 * q + 1] = (xv.y > 0.f) ? 0xFFFFFFFFu : 0x7FFFFFFFu;
            ymask[4 * q + 2] = (xv.z > 0.f) ? 0xFFFFFFFFu : 0x7FFFFFFFu;
            ymask[4 * q + 3] = (xv.w > 0.f) ? 0xFFFFFFFFu : 0x7FFFFFFFu;
        }
    }
    const int* __restrict__ perm_b = perms + (size_t)b * T;

    float pf[E];                   // prefetched row fragment
    int pf_i = -1;
    unsigned r = 0;                // global round parity (never reset)

    for (int base = 0; base < T; base += WIN) {
        const int epoch = (base >> 10) + 1;
        // scatter inverse map (window = permutation slice, indices distinct)
        const int4 iv = ((const int4*)(perm_b + base))[tid];
        wpos[iv.x] = (epoch << 10) | (4 * tid + 0);
        wpos[iv.y] = (epoch << 10) | (4 * tid + 1);
        wpos[iv.z] = (epoch << 10) | (4 * tid + 2);
        wpos[iv.w] = (epoch << 10) | (4 * tid + 3);
        lds_barrier();
        // build static keys for the 16 owned elems
#pragma unroll
        for (int q = 0; q < 4; ++q) {
            const int4 wp = ((const int4*)wpos)[4 * tid + q];
            const int e0 = 4 * q;
            const unsigned i0 = (unsigned)(E * tid + e0);
            sk[e0 + 0] = ((wp.x >> 10) == epoch)
                ? (((unsigned)(wp.x & 1023) << 14) | ((i0 + 0) << 2) | ((ymask[e0 + 0] >> 30) & 2u)) : INFK;
            sk[e0 + 1] = ((wp.y >> 10) == epoch)
                ? (((unsigned)(wp.y & 1023) << 14) | ((i0 + 1) << 2) | ((ymask[e0 + 1] >> 30) & 2u)) : INFK;
            sk[e0 + 2] = ((wp.z >> 10) == epoch)
                ? (((unsigned)(wp.z & 1023) << 14) | ((i0 + 2) << 2) | ((ymask[e0 + 2] >> 30) & 2u)) : INFK;
            sk[e0 + 3] = ((wp.w >> 10) == epoch)
                ? (((unsigned)(wp.w & 1023) << 14) | ((i0 + 3) << 2) | ((ymask[e0 + 3] >> 30) & 2u)) : INFK;
        }

        unsigned ck = 0;
        // round-0 pure scan
        unsigned key = INFK;
#pragma unroll
        for (int k = 0; k < E; ++k) {
            const unsigned t2 = ((unsigned)__double2hiint(zj[k])) ^ ymask[k];
            const unsigned cand = (sk[k] | (unsigned)(((int)t2) >> 31)) - ck;
            key = umin2(key, cand);
        }

        for (;;) {
            // ---- wave min via DPP (no LDS round trips) ----
            const unsigned m1 = wave_min64(key);
            const unsigned p = r & 1u; r++;
            if (lane == 0) ((unsigned*)&slot1v[p])[wid] = m1;
            // ---- wave 2nd min (winner lane masked; keys are unique) ----
            const unsigned m2 = wave_min64((key == m1) ? INFK : key);
            if (lane == 0) ((unsigned*)&slot2v[p])[wid] = m2;
            lds_barrier();

            // ---- exact global top-2 from the 8 published values ----
            const uint4 s1 = slot1v[p];
            const unsigned g = umin2(umin2(s1.x, s1.y), umin2(s1.z, s1.w));
            if (g >= LIMIT) break;   // no valid future candidate (uniform)
            const uint4 s2 = slot2v[p];
            const unsigned o0 = (s1.x == g) ? s2.x : s1.x;
            const unsigned o1 = (s1.y == g) ? s2.y : s1.y;
            const unsigned o2 = (s1.z == g) ? s2.z : s1.z;
            const unsigned o3 = (s1.w == g) ? s2.w : s1.w;
            const unsigned g2 = umin2(umin2(o0, o1), umin2(o2, o3));

            const unsigned wk = g + ck;
            const int istar = (int)((wk >> 2) & 4095u);
            const int y1 = (int)(wk & 3u) - 1;
            const double d = (double)(-2 * y1);   // mismatch => s = -y
            const unsigned ck_old = ck;
            ck = ((wk >> 14) + 1u) << 14;

            // ---- winner row: issue load early ----
            const bool hit = (istar == pf_i);     // uniform
            float wr[E];
            const float4* __restrict__ rowp = (const float4*)(W + (size_t)istar * N) + 4 * tid;
            if (!hit) {
                const float4 a = rowp[0], c = rowp[1], e = rowp[2], f = rowp[3];
                wr[0] = a.x;  wr[1] = a.y;  wr[2] = a.z;  wr[3] = a.w;
                wr[4] = c.x;  wr[5] = c.y;  wr[6] = c.z;  wr[7] = c.w;
                wr[8] = e.x;  wr[9] = e.y;  wr[10] = e.z; wr[11] = e.w;
                wr[12] = f.x; wr[13] = f.y; wr[14] = f.z; wr[15] = f.w;
            } else {
#pragma unroll
                for (int k = 0; k < E; ++k) wr[k] = pf[k];
            }
            // ---- exact next-candidate prefetch (overlaps apply + reduce) ----
            if (g2 < LIMIT) {
                const int i2 = (int)(((g2 + ck_old) >> 2) & 4095u);
                const float4* __restrict__ r2 = (const float4*)(W + (size_t)i2 * N) + 4 * tid;
                const float4 a = r2[0], c = r2[1], e = r2[2], f = r2[3];
                pf[0] = a.x;  pf[1] = a.y;  pf[2] = a.z;  pf[3] = a.w;
                pf[4] = c.x;  pf[5] = c.y;  pf[6] = c.z;  pf[7] = c.w;
                pf[8] = e.x;  pf[9] = e.y;  pf[10] = e.z; pf[11] = e.w;
                pf[12] = f.x; pf[13] = f.y; pf[14] = f.z; pf[15] = f.w;
                pf_i = i2;
            }

            // ---- owner fixup (1 thread) ----
            if (tid == (istar >> 4)) {
                const int kk = istar & 15;
#pragma unroll
                for (int k = 0; k < E; ++k)
                    if (k == kk) { ymask[k] ^= 0x80000000u; sk[k] ^= 2u; }
            }

            // ---- fused apply + scan for next winner ----
            key = INFK;
#pragma unroll
            for (int k = 0; k < E; ++k) {
                zj[k] += d * (double)wr[k];   // W[istar][istar]==0 -> owner safe
                const unsigned t2 = ((unsigned)__double2hiint(zj[k])) ^ ymask[k];
                const unsigned cand = (sk[k] | (unsigned)(((int)t2) >> 31)) - ck;
                key = umin2(key, cand);
            }
        }
    }

    // ---- output: y = +1 if ymask top bit set else -1 ----
    float4* __restrict__ os = (float4*)(out + (size_t)b * N);
#pragma unroll
    for (int q = 0; q < 4; ++q) {
        float4 o;
        o.x = (ymask[4 * q + 0] & 0x80000000u) ? 1.0f : -1.0f;
        o.y = (ymask[4 * q + 1] & 0x80000000u) ? 1.0f : -1.0f;
        o.z = (ymask[4 * q + 2] & 0x80000000u) ? 1.0f : -1.0f;
        o.w = (ymask[4 * q + 3] & 0x80000000u) ? 1.0f : -1.0f;
        os[4 * tid + q] = o;
    }
}

extern "C" void kernel_launch(void* const* d_in, const int* in_sizes, int n_in,
                              void* d_out, int out_size, void* d_ws, size_t ws_size,
                              hipStream_t stream) {
    const float* x = (const float*)d_in[0];      // [B, N] f32, bipolar
    const float* W = (const float*)d_in[1];      // [N, N] f32, symmetric, zero diag
    const int* perms = (const int*)d_in[2];      // [B, ITERS, N] i32
    float* out = (float*)d_out;                  // [B, N] f32
    double* Z0 = (double*)d_ws;                  // B*N doubles = 256 KB scratch

    hipLaunchKernelGGL(z0_gemv, dim3(N), dim3(256), 0, stream, W, x, Z0);
    hipLaunchKernelGGL(hop_seq, dim3(B), dim3(NT), 0, stream, W, x, perms, Z0, out);
}